// Round 1
// baseline (2223.206 us; speedup 1.0000x reference)
//
#include <hip/hip_runtime.h>
#include <math.h>

#define BATCH 4
#define S_LEN 2048
#define DM    1024
#define NH    16
#define DK    64

// ---------------------------------------------------------------------------
// GEMM: C[m,n] = sum_k X[m,k] * W[n,k]
//   X: [M,K] row-major, W: [N,K] row-major (i.e. C = X @ W^T), C: [M,N]
// 128x128 tile, BK=16, 256 threads, 8x8 micro-tile split into 4+4 (stride-64)
// so LDS reads are conflict-free float4.
// ---------------------------------------------------------------------------
__global__ __launch_bounds__(256, 2)
void gemm_nt_128(const float* __restrict__ X, const float* __restrict__ W,
                 float* __restrict__ C, int M, int N, int K)
{
    __shared__ float Xs[16][132];   // [k][m] k-major, pad 132 (528B, 16B-aligned)
    __shared__ float Ws[16][132];   // [k][n]

    const int tid = threadIdx.x;
    const int tx = tid & 15;    // column group
    const int ty = tid >> 4;    // row group
    const int bm = blockIdx.y * 128;
    const int bn = blockIdx.x * 128;

    float acc[8][8];
#pragma unroll
    for (int i = 0; i < 8; ++i)
#pragma unroll
        for (int j = 0; j < 8; ++j) acc[i][j] = 0.f;

    const float* Xb = X + (size_t)bm * K;
    const float* Wb = W + (size_t)bn * K;

    for (int kt = 0; kt < K; kt += 16) {
        // load 128x16 tiles: 512 float4 per operand, 2 per thread
#pragma unroll
        for (int l = 0; l < 2; ++l) {
            int pos = tid + l * 256;       // 0..511
            int row = pos >> 2;            // 0..127
            int k4  = (pos & 3) << 2;      // 0,4,8,12
            float4 xv = *(const float4*)(Xb + (size_t)row * K + kt + k4);
            Xs[k4 + 0][row] = xv.x; Xs[k4 + 1][row] = xv.y;
            Xs[k4 + 2][row] = xv.z; Xs[k4 + 3][row] = xv.w;
            float4 wv = *(const float4*)(Wb + (size_t)row * K + kt + k4);
            Ws[k4 + 0][row] = wv.x; Ws[k4 + 1][row] = wv.y;
            Ws[k4 + 2][row] = wv.z; Ws[k4 + 3][row] = wv.w;
        }
        __syncthreads();
#pragma unroll
        for (int k = 0; k < 16; ++k) {
            float a[8], b[8];
            *(float4*)&a[0] = *(const float4*)&Xs[k][ty * 4];
            *(float4*)&a[4] = *(const float4*)&Xs[k][ty * 4 + 64];
            *(float4*)&b[0] = *(const float4*)&Ws[k][tx * 4];
            *(float4*)&b[4] = *(const float4*)&Ws[k][tx * 4 + 64];
#pragma unroll
            for (int i = 0; i < 8; ++i)
#pragma unroll
                for (int j = 0; j < 8; ++j)
                    acc[i][j] = fmaf(a[i], b[j], acc[i][j]);
        }
        __syncthreads();
    }

#pragma unroll
    for (int i = 0; i < 8; ++i) {
        int lr = (i < 4) ? (ty * 4 + i) : (64 + ty * 4 + (i - 4));
        float* Cr = C + (size_t)(bm + lr) * N + bn;
        float4 v0 = make_float4(acc[i][0], acc[i][1], acc[i][2], acc[i][3]);
        float4 v1 = make_float4(acc[i][4], acc[i][5], acc[i][6], acc[i][7]);
        *(float4*)(Cr + tx * 4)      = v0;
        *(float4*)(Cr + 64 + tx * 4) = v1;
    }
}

// ---------------------------------------------------------------------------
// Flash-style causal attention.
// Q/K/V/O layouts: [B, S, DM] with head h occupying columns h*64..h*64+63.
// Block = (row-tile rt of 64 query rows) x (b*NH + h). 256 threads.
// Thread (ty,tx): rows ty*4+ri (64 rows), cols tx*4+ci (keys or d).
// ---------------------------------------------------------------------------
__global__ __launch_bounds__(256, 2)
void attn_causal(const float* __restrict__ Qg, const float* __restrict__ Kg,
                 const float* __restrict__ Vg, float* __restrict__ Og)
{
    __shared__ float Qt[64][68];   // [k][r]  (k-major, pre-scaled by 1/8)
    __shared__ float Kt[64][68];   // [k][c]
    __shared__ float Vs[64][68];   // [j][d]  (row-major)
    __shared__ float Pt[64][68];   // [j][r]

    const int tid = threadIdx.x;
    const int tx = tid & 15;
    const int ty = tid >> 4;
    const int rt = blockIdx.x;            // query tile 0..31
    const int bh = blockIdx.y;            // 0..63
    const int b  = bh >> 4;
    const int h  = bh & 15;

    const size_t base = (size_t)b * S_LEN * DM + (size_t)h * DK;
    const float* Qb = Qg + base;
    const float* Kb = Kg + base;
    const float* Vb = Vg + base;
    const int row0 = rt * 64;

    // load Q tile transposed, scaled by 1/sqrt(64)
#pragma unroll
    for (int l = 0; l < 4; ++l) {
        int pos = tid + l * 256;        // 0..1023 float4 slots
        int r  = pos >> 4;              // 0..63
        int c0 = (pos & 15) << 2;       // 0..60
        float4 v = *(const float4*)(Qb + (size_t)(row0 + r) * DM + c0);
        Qt[c0 + 0][r] = v.x * 0.125f;
        Qt[c0 + 1][r] = v.y * 0.125f;
        Qt[c0 + 2][r] = v.z * 0.125f;
        Qt[c0 + 3][r] = v.w * 0.125f;
    }

    float m[4], lsum[4], o[4][4];
#pragma unroll
    for (int i = 0; i < 4; ++i) {
        m[i] = -1e30f; lsum[i] = 0.f;
#pragma unroll
        for (int j = 0; j < 4; ++j) o[i][j] = 0.f;
    }

    for (int kt = 0; kt <= rt; ++kt) {
        // stage K (transposed) and V (row-major)
#pragma unroll
        for (int l = 0; l < 4; ++l) {
            int pos = tid + l * 256;
            int r  = pos >> 4;
            int c0 = (pos & 15) << 2;
            float4 kv = *(const float4*)(Kb + (size_t)(kt * 64 + r) * DM + c0);
            Kt[c0 + 0][r] = kv.x; Kt[c0 + 1][r] = kv.y;
            Kt[c0 + 2][r] = kv.z; Kt[c0 + 3][r] = kv.w;
            float4 vv = *(const float4*)(Vb + (size_t)(kt * 64 + r) * DM + c0);
            *(float4*)&Vs[r][c0] = vv;
        }
        __syncthreads();

        // scores s[ri][ci] = sum_k Qt[k][row] * Kt[k][col]
        float s[4][4];
#pragma unroll
        for (int i = 0; i < 4; ++i)
#pragma unroll
            for (int j = 0; j < 4; ++j) s[i][j] = 0.f;

#pragma unroll 16
        for (int k = 0; k < 64; ++k) {
            float a[4], bb[4];
            *(float4*)a  = *(const float4*)&Qt[k][ty * 4];
            *(float4*)bb = *(const float4*)&Kt[k][tx * 4];
#pragma unroll
            for (int ri = 0; ri < 4; ++ri)
#pragma unroll
                for (int ci = 0; ci < 4; ++ci)
                    s[ri][ci] = fmaf(a[ri], bb[ci], s[ri][ci]);
        }

        if (kt == rt) {  // causal mask on the diagonal tile
#pragma unroll
            for (int ri = 0; ri < 4; ++ri)
#pragma unroll
                for (int ci = 0; ci < 4; ++ci)
                    if (tx * 4 + ci > ty * 4 + ri) s[ri][ci] = -1e30f;
        }

        // online softmax update
        float rowmax[4], rowsum[4], p[4][4];
#pragma unroll
        for (int ri = 0; ri < 4; ++ri) {
            rowmax[ri] = fmaxf(fmaxf(s[ri][0], s[ri][1]), fmaxf(s[ri][2], s[ri][3]));
#pragma unroll
            for (int off = 8; off >= 1; off >>= 1)
                rowmax[ri] = fmaxf(rowmax[ri], __shfl_xor(rowmax[ri], off));
        }
        float rs[4];
#pragma unroll
        for (int ri = 0; ri < 4; ++ri) {
            float mnew = fmaxf(m[ri], rowmax[ri]);
            rs[ri] = __expf(m[ri] - mnew);
            m[ri] = mnew;
            rowsum[ri] = 0.f;
#pragma unroll
            for (int ci = 0; ci < 4; ++ci) {
                p[ri][ci] = __expf(s[ri][ci] - mnew);
                rowsum[ri] += p[ri][ci];
            }
#pragma unroll
            for (int off = 8; off >= 1; off >>= 1)
                rowsum[ri] += __shfl_xor(rowsum[ri], off);
            lsum[ri] = lsum[ri] * rs[ri] + rowsum[ri];
#pragma unroll
            for (int ci = 0; ci < 4; ++ci) o[ri][ci] *= rs[ri];
        }

        // publish P transposed: Pt[j][r]
#pragma unroll
        for (int ri = 0; ri < 4; ++ri)
#pragma unroll
            for (int ci = 0; ci < 4; ++ci)
                Pt[tx * 4 + ci][ty * 4 + ri] = p[ri][ci];
        __syncthreads();

        // O += P @ V
#pragma unroll 16
        for (int j = 0; j < 64; ++j) {
            float a[4], bb[4];
            *(float4*)a  = *(const float4*)&Pt[j][ty * 4];
            *(float4*)bb = *(const float4*)&Vs[j][tx * 4];
#pragma unroll
            for (int ri = 0; ri < 4; ++ri)
#pragma unroll
                for (int ci = 0; ci < 4; ++ci)
                    o[ri][ci] = fmaf(a[ri], bb[ci], o[ri][ci]);
        }
        __syncthreads();
    }

    // epilogue: divide by l, store
    float* Ob = Og + base;
#pragma unroll
    for (int ri = 0; ri < 4; ++ri) {
        float inv = 1.f / lsum[ri];
        float4 v = make_float4(o[ri][0] * inv, o[ri][1] * inv,
                               o[ri][2] * inv, o[ri][3] * inv);
        *(float4*)(Ob + (size_t)(row0 + ty * 4 + ri) * DM + tx * 4) = v;
    }
}

// ---------------------------------------------------------------------------
extern "C" void kernel_launch(void* const* d_in, const int* in_sizes, int n_in,
                              void* d_out, int out_size, void* d_ws, size_t ws_size,
                              hipStream_t stream)
{
    const float* q   = (const float*)d_in[0];
    // d_in[1] = causal mask (int32), known statically -> ignored
    const float* w_q = (const float*)d_in[2];
    const float* w_k = (const float*)d_in[3];
    const float* w_v = (const float*)d_in[4];
    const float* w_o = (const float*)d_in[5];
    float* out = (float*)d_out;

    const size_t MN = (size_t)BATCH * S_LEN * DM;   // 8388608 elements
    float* Qw = (float*)d_ws;
    float* Kw = Qw + MN;
    float* Vw = Kw + MN;
    // Attention output aliases the Q buffer: each attn block reads exactly the
    // Q region it later writes (block-exclusive rows x head-cols), reads happen
    // (into LDS) before the epilogue store. Keeps ws usage at 96 MB.
    float* Ow = Qw;

    const int M = BATCH * S_LEN;            // 8192
    dim3 blk(256);
    dim3 ggrid(DM / 128, M / 128);          // (8, 64)
    gemm_nt_128<<<ggrid, blk, 0, stream>>>(q, w_q, Qw, M, DM, DM);
    gemm_nt_128<<<ggrid, blk, 0, stream>>>(q, w_k, Kw, M, DM, DM);
    gemm_nt_128<<<ggrid, blk, 0, stream>>>(q, w_v, Vw, M, DM, DM);

    dim3 agrid(S_LEN / 64, BATCH * NH);     // (32, 64)
    attn_causal<<<agrid, blk, 0, stream>>>(Qw, Kw, Vw, Ow);

    gemm_nt_128<<<ggrid, blk, 0, stream>>>(Ow, w_o, out, M, DM, DM);
}

// Round 5
// 880.455 us; speedup vs baseline: 2.5251x; 2.5251x over previous
//
#include <hip/hip_runtime.h>
#include <math.h>

#define BATCH 4
#define S_LEN 2048
#define DM    1024
#define NH    16
#define DK    64

typedef __attribute__((ext_vector_type(8))) short short8;
typedef __attribute__((ext_vector_type(4))) float f32x4;

static __device__ __forceinline__ unsigned short bf_hi(float x) {
    union { float f; unsigned u; } c; c.f = x;
    return (unsigned short)(c.u >> 16);          // truncate; residual goes to lo
}
static __device__ __forceinline__ float bf_f(unsigned short h) {
    union { unsigned u; float f; } c; c.u = ((unsigned)h) << 16;
    return c.f;
}
static __device__ __forceinline__ unsigned short bf_rnd(float x) {
    union { float f; unsigned u; } c; c.f = x;
    unsigned r = c.u + 0x7fffu + ((c.u >> 16) & 1u);
    return (unsigned short)(r >> 16);
}

// ---------------------------------------------------------------------------
// Split-bf16 GEMM: C[m,n] = sum_k X[m,k]*W[n,k]  (C = X @ W^T), fp32 in/out.
// 128x128 tile, BK=32, 256 thr / 4 waves, each wave 64x64 out (4x4 MFMA tiles).
// 3-term split: Xh*Wh + Xh*Wl + Xl*Wh  -> ~2^-16 relative error.
// ---------------------------------------------------------------------------
__global__ __launch_bounds__(256, 2)
void gemm_bf16x3(const float* __restrict__ X, const float* __restrict__ W,
                 float* __restrict__ C, int M, int N, int K)
{
    __shared__ unsigned short Xh[128][40], Xl[128][40];
    __shared__ unsigned short Wh[128][40], Wl[128][40];

    const int tid  = threadIdx.x;
    const int lane = tid & 63;
    const int wid  = tid >> 6;
    const int lrow = lane & 15;
    const int lgrp = lane >> 4;
    const int bm = blockIdx.y * 128;
    const int bn = blockIdx.x * 128;
    const int wm = (wid & 1) * 64;
    const int wn = (wid >> 1) * 64;

    const f32x4 fzero = {0.f, 0.f, 0.f, 0.f};
    f32x4 acc[4][4];
#pragma unroll
    for (int i = 0; i < 4; ++i)
#pragma unroll
        for (int j = 0; j < 4; ++j) acc[i][j] = fzero;

    const int srow = tid >> 2;          // staging row (i=0); +64 for i=1
    const int sc8  = (tid & 3) * 8;     // k-chunk within BK=32

    for (int kt = 0; kt < K; kt += 32) {
#pragma unroll
        for (int i = 0; i < 2; ++i) {
            const int row = srow + i * 64;
            const float* xp = X + (size_t)(bm + row) * K + kt + sc8;
            const float* wp = W + (size_t)(bn + row) * K + kt + sc8;
            float4 a0 = *(const float4*)xp, a1 = *(const float4*)(xp + 4);
            float4 b0 = *(const float4*)wp, b1 = *(const float4*)(wp + 4);
            float va[8] = {a0.x,a0.y,a0.z,a0.w,a1.x,a1.y,a1.z,a1.w};
            float vb[8] = {b0.x,b0.y,b0.z,b0.w,b1.x,b1.y,b1.z,b1.w};
            short8 xh, xl, wh, wl;
#pragma unroll
            for (int j = 0; j < 8; ++j) {
                unsigned short h = bf_hi(va[j]);
                xh[j] = (short)h; xl[j] = (short)bf_hi(va[j] - bf_f(h));
                unsigned short g = bf_hi(vb[j]);
                wh[j] = (short)g; wl[j] = (short)bf_hi(vb[j] - bf_f(g));
            }
            *(short8*)&Xh[row][sc8] = xh; *(short8*)&Xl[row][sc8] = xl;
            *(short8*)&Wh[row][sc8] = wh; *(short8*)&Wl[row][sc8] = wl;
        }
        __syncthreads();

        short8 ah[4], al[4], bh[4], bl[4];
#pragma unroll
        for (int t = 0; t < 4; ++t) {
            ah[t] = *(const short8*)&Xh[wm + t*16 + lrow][lgrp*8];
            al[t] = *(const short8*)&Xl[wm + t*16 + lrow][lgrp*8];
            bh[t] = *(const short8*)&Wh[wn + t*16 + lrow][lgrp*8];
            bl[t] = *(const short8*)&Wl[wn + t*16 + lrow][lgrp*8];
        }
#pragma unroll
        for (int mt = 0; mt < 4; ++mt)
#pragma unroll
            for (int nt = 0; nt < 4; ++nt) {
                acc[mt][nt] = __builtin_amdgcn_mfma_f32_16x16x32_bf16(ah[mt], bh[nt], acc[mt][nt], 0, 0, 0);
                acc[mt][nt] = __builtin_amdgcn_mfma_f32_16x16x32_bf16(ah[mt], bl[nt], acc[mt][nt], 0, 0, 0);
                acc[mt][nt] = __builtin_amdgcn_mfma_f32_16x16x32_bf16(al[mt], bh[nt], acc[mt][nt], 0, 0, 0);
            }
        __syncthreads();
    }

#pragma unroll
    for (int mt = 0; mt < 4; ++mt)
#pragma unroll
        for (int nt = 0; nt < 4; ++nt)
#pragma unroll
            for (int r = 0; r < 4; ++r)
                C[(size_t)(bm + wm + mt*16 + lgrp*4 + r) * N + bn + wn + nt*16 + lrow]
                    = acc[mt][nt][r];
}

// ---------------------------------------------------------------------------
// MFMA flash attention, causal. Layout [B, S, DM], head h = cols h*64..h*64+63.
// Block: 64 q-rows x (b,h); 4 waves x 16 q-rows each; KV tile 64.
// QK^T: Q,K split 3-term. PV: P plain bf16 (round), V split 2-term.
// Softmax in D-fragment layout; row stats via 16-lane __shfl_xor.
// ---------------------------------------------------------------------------
__global__ __launch_bounds__(256, 2)
void attn_mfma(const float* __restrict__ Qg, const float* __restrict__ Kg,
               const float* __restrict__ Vg, float* __restrict__ Og)
{
    __shared__ unsigned short Ksh[64][72], Ksl[64][72];  // [key][d]
    __shared__ unsigned short Vth[64][72], Vtl[64][72];  // [d][key] (transposed)
    __shared__ unsigned short Ps[4][16][72];             // per-wave P [q][key]

    const int tid  = threadIdx.x;
    const int lane = tid & 63;
    const int wid  = tid >> 6;
    const int lrow = lane & 15;
    const int lgrp = lane >> 4;

    const int rt = (int)(gridDim.x - 1u - blockIdx.x);   // long jobs first
    const int bh = blockIdx.y;
    const int b  = bh >> 4;
    const int h  = bh & 15;

    const size_t base = (size_t)b * S_LEN * DM + (size_t)h * DK;
    const int row0 = rt * 64;

    // Q fragments: rows row0 + wid*16 + lrow, pre-scaled by 1/8, split hi/lo
    short8 qh[2], ql[2];
#pragma unroll
    for (int c = 0; c < 2; ++c) {
        const float* qp = Qg + base + (size_t)(row0 + wid*16 + lrow) * DM + c*32 + lgrp*8;
        float4 a0 = *(const float4*)qp, a1 = *(const float4*)(qp + 4);
        float v[8] = {a0.x,a0.y,a0.z,a0.w,a1.x,a1.y,a1.z,a1.w};
#pragma unroll
        for (int j = 0; j < 8; ++j) {
            float x = v[j] * 0.125f;
            unsigned short hh = bf_hi(x);
            qh[c][j] = (short)hh;
            ql[c][j] = (short)bf_hi(x - bf_f(hh));
        }
    }

    const f32x4 fzero = {0.f, 0.f, 0.f, 0.f};
    f32x4 o[4];
    float m[4], l[4];
#pragma unroll
    for (int i = 0; i < 4; ++i) { o[i] = fzero; m[i] = -1e30f; l[i] = 0.f; }

    const int kkey = tid >> 3;           // K staging: key (i adds 32)
    const int kc8  = (tid & 7) * 8;      // d-chunk
    const int vk0  = (tid >> 4) * 4;     // V staging: 4x4 block key base
    const int vd0  = (tid & 15) * 4;     // 4x4 block d base

    for (int kt = 0; kt <= rt; ++kt) {
        const float* Kb = Kg + base + (size_t)(kt * 64) * DM;
        const float* Vb = Vg + base + (size_t)(kt * 64) * DM;

        // --- stage K hi/lo, row-major [key][d]
#pragma unroll
        for (int i = 0; i < 2; ++i) {
            const int key = kkey + i * 32;
            const float* kp = Kb + (size_t)key * DM + kc8;
            float4 a0 = *(const float4*)kp, a1 = *(const float4*)(kp + 4);
            float v[8] = {a0.x,a0.y,a0.z,a0.w,a1.x,a1.y,a1.z,a1.w};
            short8 hh, ll;
#pragma unroll
            for (int j = 0; j < 8; ++j) {
                unsigned short t = bf_hi(v[j]);
                hh[j] = (short)t; ll[j] = (short)bf_hi(v[j] - bf_f(t));
            }
            *(short8*)&Ksh[key][kc8] = hh;
            *(short8*)&Ksl[key][kc8] = ll;
        }
        // --- stage V transposed [d][key] via 4x4 in-register transpose
        {
            float4 vv[4];
#pragma unroll
            for (int kk = 0; kk < 4; ++kk)
                vv[kk] = *(const float4*)(Vb + (size_t)(vk0 + kk) * DM + vd0);
#pragma unroll
            for (int j = 0; j < 4; ++j) {
                unsigned short h4[4], g4[4];
#pragma unroll
                for (int kk = 0; kk < 4; ++kk) {
                    float x = ((const float*)&vv[kk])[j];
                    h4[kk] = bf_hi(x);
                    g4[kk] = bf_hi(x - bf_f(h4[kk]));
                }
                uint2 wh, wl;
                wh.x = (unsigned)h4[0] | ((unsigned)h4[1] << 16);
                wh.y = (unsigned)h4[2] | ((unsigned)h4[3] << 16);
                wl.x = (unsigned)g4[0] | ((unsigned)g4[1] << 16);
                wl.y = (unsigned)g4[2] | ((unsigned)g4[3] << 16);
                *(uint2*)&Vth[vd0 + j][vk0] = wh;
                *(uint2*)&Vtl[vd0 + j][vk0] = wl;
            }
        }
        __syncthreads();

        // --- S = (Q/8) K^T : 4 key-tiles x 2 k-chunks x 3 split terms
        f32x4 s[4];
#pragma unroll
        for (int t = 0; t < 4; ++t) s[t] = fzero;
#pragma unroll
        for (int t = 0; t < 4; ++t)
#pragma unroll
            for (int c = 0; c < 2; ++c) {
                short8 kh = *(const short8*)&Ksh[t*16 + lrow][c*32 + lgrp*8];
                short8 kl = *(const short8*)&Ksl[t*16 + lrow][c*32 + lgrp*8];
                s[t] = __builtin_amdgcn_mfma_f32_16x16x32_bf16(qh[c], kh, s[t], 0, 0, 0);
                s[t] = __builtin_amdgcn_mfma_f32_16x16x32_bf16(ql[c], kh, s[t], 0, 0, 0);
                s[t] = __builtin_amdgcn_mfma_f32_16x16x32_bf16(qh[c], kl, s[t], 0, 0, 0);
            }

        if (kt == rt) {                  // causal mask on the diagonal tile
            const int qloc = wid * 16 + lgrp * 4;
#pragma unroll
            for (int t = 0; t < 4; ++t)
#pragma unroll
                for (int r = 0; r < 4; ++r)
                    if (t*16 + lrow > qloc + r) s[t][r] = -1e30f;
        }

        // --- online softmax (rows = lgrp*4+r; keys spread over lrow & tiles)
        float pm[4];
#pragma unroll
        for (int r = 0; r < 4; ++r)
            pm[r] = fmaxf(fmaxf(s[0][r], s[1][r]), fmaxf(s[2][r], s[3][r]));
#pragma unroll
        for (int off = 8; off >= 1; off >>= 1)
#pragma unroll
            for (int r = 0; r < 4; ++r)
                pm[r] = fmaxf(pm[r], __shfl_xor(pm[r], off));

        float rs[4], rowsum[4];
#pragma unroll
        for (int r = 0; r < 4; ++r) {
            float mn = fmaxf(m[r], pm[r]);
            rs[r] = __expf(m[r] - mn);
            m[r] = mn;
            rowsum[r] = 0.f;
        }
#pragma unroll
        for (int t = 0; t < 4; ++t)
#pragma unroll
            for (int r = 0; r < 4; ++r) {
                float p = __expf(s[t][r] - m[r]);
                s[t][r] = p;
                rowsum[r] += p;
            }
#pragma unroll
        for (int off = 8; off >= 1; off >>= 1)
#pragma unroll
            for (int r = 0; r < 4; ++r)
                rowsum[r] += __shfl_xor(rowsum[r], off);
#pragma unroll
        for (int r = 0; r < 4; ++r) l[r] = l[r] * rs[r] + rowsum[r];
#pragma unroll
        for (int dt = 0; dt < 4; ++dt)
#pragma unroll
            for (int r = 0; r < 4; ++r) o[dt][r] *= rs[r];

        // --- publish P as bf16 (wave-private)
#pragma unroll
        for (int t = 0; t < 4; ++t)
#pragma unroll
            for (int r = 0; r < 4; ++r)
                Ps[wid][lgrp*4 + r][t*16 + lrow] = bf_rnd(s[t][r]);

        // --- O += P V (V 2-term split)
#pragma unroll
        for (int kc = 0; kc < 2; ++kc) {
            short8 pa = *(const short8*)&Ps[wid][lrow][kc*32 + lgrp*8];
#pragma unroll
            for (int dt = 0; dt < 4; ++dt) {
                short8 vh = *(const short8*)&Vth[dt*16 + lrow][kc*32 + lgrp*8];
                short8 vl = *(const short8*)&Vtl[dt*16 + lrow][kc*32 + lgrp*8];
                o[dt] = __builtin_amdgcn_mfma_f32_16x16x32_bf16(pa, vh, o[dt], 0, 0, 0);
                o[dt] = __builtin_amdgcn_mfma_f32_16x16x32_bf16(pa, vl, o[dt], 0, 0, 0);
            }
        }
        __syncthreads();
    }

    // --- epilogue
    float* Ob = Og + base;
#pragma unroll
    for (int r = 0; r < 4; ++r) {
        float inv = 1.f / l[r];
#pragma unroll
        for (int dt = 0; dt < 4; ++dt)
            Ob[(size_t)(row0 + wid*16 + lgrp*4 + r) * DM + dt*16 + lrow] = o[dt][r] * inv;
    }
}

// ---------------------------------------------------------------------------
extern "C" void kernel_launch(void* const* d_in, const int* in_sizes, int n_in,
                              void* d_out, int out_size, void* d_ws, size_t ws_size,
                              hipStream_t stream)
{
    const float* q   = (const float*)d_in[0];
    // d_in[1] = causal mask (static) -> ignored
    const float* w_q = (const float*)d_in[2];
    const float* w_k = (const float*)d_in[3];
    const float* w_v = (const float*)d_in[4];
    const float* w_o = (const float*)d_in[5];
    float* out = (float*)d_out;

    const size_t MN = (size_t)BATCH * S_LEN * DM;
    float* Qw = (float*)d_ws;
    float* Kw = Qw + MN;
    float* Vw = Kw + MN;
    // Attention output aliases Qw: each attn block reads exactly the Q region
    // (rows x head-cols) it later writes; regions are block-exclusive.
    float* Ow = Qw;

    const int M = BATCH * S_LEN;            // 8192
    dim3 blk(256);
    dim3 ggrid(DM / 128, M / 128);          // (8, 64)
    gemm_bf16x3<<<ggrid, blk, 0, stream>>>(q, w_q, Qw, M, DM, DM);
    gemm_bf16x3<<<ggrid, blk, 0, stream>>>(q, w_k, Kw, M, DM, DM);
    gemm_bf16x3<<<ggrid, blk, 0, stream>>>(q, w_v, Vw, M, DM, DM);

    dim3 agrid(S_LEN / 64, BATCH * NH);     // (32, 64)
    attn_mfma<<<agrid, blk, 0, stream>>>(Qw, Kw, Vw, Ow);

    gemm_bf16x3<<<ggrid, blk, 0, stream>>>(Ow, w_o, out, M, DM, DM);
}

// Round 9
// 756.636 us; speedup vs baseline: 2.9383x; 1.1636x over previous
//
#include <hip/hip_runtime.h>
#include <math.h>

#define BATCH 4
#define S_LEN 2048
#define DM    1024
#define NH    16
#define DK    64

typedef __attribute__((ext_vector_type(8))) short short8;
typedef __attribute__((ext_vector_type(4))) float f32x4;

static __device__ __forceinline__ unsigned short bf_hi(float x) {
    union { float f; unsigned u; } c; c.f = x;
    return (unsigned short)(c.u >> 16);          // truncate; residual goes to lo
}
static __device__ __forceinline__ float bf_f(unsigned short h) {
    union { unsigned u; float f; } c; c.u = ((unsigned)h) << 16;
    return c.f;
}
static __device__ __forceinline__ unsigned short bf_rnd(float x) {
    union { float f; unsigned u; } c; c.f = x;
    unsigned r = c.u + 0x7fffu + ((c.u >> 16) & 1u);
    return (unsigned short)(r >> 16);
}

// ---------------------------------------------------------------------------
// Split-bf16 GEMM core: C = A @ W^T (both K-contiguous), 128x128 tile, BK=32,
// 4 waves, 4x4 MFMA tiles/wave, 3-term split product.
// PRESPLIT_A: A supplied as pre-split hi/lo bf16 planes (pure-copy staging).
// SPLIT_OUT : write C as hi/lo bf16 planes (with scale) instead of fp32.
// ---------------------------------------------------------------------------
template<bool PRESPLIT_A, bool SPLIT_OUT>
__global__ __launch_bounds__(256, 3)
void gemm_k(const float* __restrict__ Af,
            const unsigned short* __restrict__ Agh,
            const unsigned short* __restrict__ Agl,
            const float* __restrict__ W,
            float* __restrict__ Cf,
            unsigned short* __restrict__ Ch,
            unsigned short* __restrict__ Cl,
            float scale, int M, int N, int K)
{
    __shared__ unsigned short Xh[128][40], Xl[128][40];
    __shared__ unsigned short Wh[128][40], Wl[128][40];

    const int tid  = threadIdx.x;
    const int lane = tid & 63;
    const int wid  = tid >> 6;
    const int lrow = lane & 15;
    const int lgrp = lane >> 4;
    const int bm = blockIdx.y * 128;
    const int bn = blockIdx.x * 128;
    const int wm = (wid & 1) * 64;
    const int wn = (wid >> 1) * 64;

    const f32x4 fzero = {0.f, 0.f, 0.f, 0.f};
    f32x4 acc[4][4];
#pragma unroll
    for (int i = 0; i < 4; ++i)
#pragma unroll
        for (int j = 0; j < 4; ++j) acc[i][j] = fzero;

    const int srow = tid >> 2;          // conversion staging: row (i adds 64)
    const int sc8  = (tid & 3) * 8;     // k-chunk within BK=32

    for (int kt = 0; kt < K; kt += 32) {
        // ---- A staging
        if constexpr (PRESPLIT_A) {
#pragma unroll
            for (int p = 0; p < 2; ++p) {
                int pos = tid + p * 256;      // 0..511
                int row = pos >> 2;           // 0..127
                int c8  = (pos & 3) * 8;
                *(short8*)&Xh[row][c8] =
                    *(const short8*)(Agh + (size_t)(bm + row) * K + kt + c8);
                *(short8*)&Xl[row][c8] =
                    *(const short8*)(Agl + (size_t)(bm + row) * K + kt + c8);
            }
        } else {
#pragma unroll
            for (int i = 0; i < 2; ++i) {
                const int row = srow + i * 64;
                const float* xp = Af + (size_t)(bm + row) * K + kt + sc8;
                float4 a0 = *(const float4*)xp, a1 = *(const float4*)(xp + 4);
                float va[8] = {a0.x,a0.y,a0.z,a0.w,a1.x,a1.y,a1.z,a1.w};
                short8 xh, xl;
#pragma unroll
                for (int j = 0; j < 8; ++j) {
                    unsigned short h = bf_hi(va[j]);
                    xh[j] = (short)h; xl[j] = (short)bf_hi(va[j] - bf_f(h));
                }
                *(short8*)&Xh[row][sc8] = xh; *(short8*)&Xl[row][sc8] = xl;
            }
        }
        // ---- W staging (fp32 -> split)
#pragma unroll
        for (int i = 0; i < 2; ++i) {
            const int row = srow + i * 64;
            const float* wp = W + (size_t)(bn + row) * K + kt + sc8;
            float4 b0 = *(const float4*)wp, b1 = *(const float4*)(wp + 4);
            float vb[8] = {b0.x,b0.y,b0.z,b0.w,b1.x,b1.y,b1.z,b1.w};
            short8 wh, wl;
#pragma unroll
            for (int j = 0; j < 8; ++j) {
                unsigned short g = bf_hi(vb[j]);
                wh[j] = (short)g; wl[j] = (short)bf_hi(vb[j] - bf_f(g));
            }
            *(short8*)&Wh[row][sc8] = wh; *(short8*)&Wl[row][sc8] = wl;
        }
        __syncthreads();

        short8 ah[4], al[4], bh[4], bl[4];
#pragma unroll
        for (int t = 0; t < 4; ++t) {
            ah[t] = *(const short8*)&Xh[wm + t*16 + lrow][lgrp*8];
            al[t] = *(const short8*)&Xl[wm + t*16 + lrow][lgrp*8];
            bh[t] = *(const short8*)&Wh[wn + t*16 + lrow][lgrp*8];
            bl[t] = *(const short8*)&Wl[wn + t*16 + lrow][lgrp*8];
        }
#pragma unroll
        for (int mt = 0; mt < 4; ++mt)
#pragma unroll
            for (int nt = 0; nt < 4; ++nt) {
                acc[mt][nt] = __builtin_amdgcn_mfma_f32_16x16x32_bf16(ah[mt], bh[nt], acc[mt][nt], 0, 0, 0);
                acc[mt][nt] = __builtin_amdgcn_mfma_f32_16x16x32_bf16(ah[mt], bl[nt], acc[mt][nt], 0, 0, 0);
                acc[mt][nt] = __builtin_amdgcn_mfma_f32_16x16x32_bf16(al[mt], bh[nt], acc[mt][nt], 0, 0, 0);
            }
        __syncthreads();
    }

#pragma unroll
    for (int mt = 0; mt < 4; ++mt)
#pragma unroll
        for (int nt = 0; nt < 4; ++nt)
#pragma unroll
            for (int r = 0; r < 4; ++r) {
                const size_t idx = (size_t)(bm + wm + mt*16 + lgrp*4 + r) * N
                                 + bn + wn + nt*16 + lrow;
                if constexpr (SPLIT_OUT) {
                    float v = acc[mt][nt][r] * scale;
                    unsigned short h = bf_hi(v);
                    Ch[idx] = h;
                    Cl[idx] = bf_hi(v - bf_f(h));
                } else {
                    Cf[idx] = acc[mt][nt][r];
                }
            }
}

// ---------------------------------------------------------------------------
// MFMA flash attention, causal. All operands pre-split bf16 [B, S, DM]
// (head h = cols h*64..h*64+63); Q pre-scaled by 1/8 in its GEMM.
// Block: 64 q-rows x (b,h); 4 waves x 16 q-rows; KV tile 64.
// Staging is pure copy/repack (no float conversion in the loop).
// Output written pre-split (hi/lo) for the o-proj GEMM.
// ---------------------------------------------------------------------------
__global__ __launch_bounds__(256, 3)
void attn_mfma(const unsigned short* __restrict__ Qh_g, const unsigned short* __restrict__ Ql_g,
               const unsigned short* __restrict__ Kh_g, const unsigned short* __restrict__ Kl_g,
               const unsigned short* __restrict__ Vh_g, const unsigned short* __restrict__ Vl_g,
               unsigned short* __restrict__ Oh_g, unsigned short* __restrict__ Ol_g)
{
    __shared__ unsigned short Ksh[64][72], Ksl[64][72];  // [key][d]
    __shared__ unsigned short Vth[64][72], Vtl[64][72];  // [d][key] (transposed)
    __shared__ unsigned short Ps[4][16][72];             // per-wave P [q][key]

    const int tid  = threadIdx.x;
    const int lane = tid & 63;
    const int wid  = tid >> 6;
    const int lrow = lane & 15;
    const int lgrp = lane >> 4;

    const int rt = (int)(gridDim.x - 1u - blockIdx.x);   // long jobs first
    const int bh = blockIdx.y;
    const int b  = bh >> 4;
    const int h  = bh & 15;

    const size_t base = (size_t)b * S_LEN * DM + (size_t)h * DK;
    const int row0 = rt * 64;

    // Q fragments: direct pre-split loads (already scaled by 1/8)
    short8 qh[2], ql[2];
#pragma unroll
    for (int c = 0; c < 2; ++c) {
        const size_t qoff = base + (size_t)(row0 + wid*16 + lrow) * DM + c*32 + lgrp*8;
        qh[c] = *(const short8*)(Qh_g + qoff);
        ql[c] = *(const short8*)(Ql_g + qoff);
    }

    const f32x4 fzero = {0.f, 0.f, 0.f, 0.f};
    f32x4 o[4];
    float m[4], l[4];
#pragma unroll
    for (int i = 0; i < 4; ++i) { o[i] = fzero; m[i] = -1e30f; l[i] = 0.f; }

    const int skey = tid >> 3;           // K staging: key (i adds 32)
    const int sc8  = (tid & 7) * 8;      // d-chunk
    const int vk0  = (tid >> 4) * 4;     // V staging: 4x4 block key base
    const int vd0  = (tid & 15) * 4;     // 4x4 block d base

    for (int kt = 0; kt <= rt; ++kt) {
        const size_t kb = base + (size_t)(kt * 64) * DM;

        // --- stage K (pure copy, both planes)
#pragma unroll
        for (int i = 0; i < 2; ++i) {
            const int key = skey + i * 32;
            const size_t off = kb + (size_t)key * DM + sc8;
            *(short8*)&Ksh[key][sc8] = *(const short8*)(Kh_g + off);
            *(short8*)&Ksl[key][sc8] = *(const short8*)(Kl_g + off);
        }
        // --- stage V transposed [d][key] via 4x4 repack (integer only)
        {
            ushort4 ah4[4], al4[4];
#pragma unroll
            for (int kk = 0; kk < 4; ++kk) {
                const size_t off = kb + (size_t)(vk0 + kk) * DM + vd0;
                ah4[kk] = *(const ushort4*)(Vh_g + off);
                al4[kk] = *(const ushort4*)(Vl_g + off);
            }
#pragma unroll
            for (int j = 0; j < 4; ++j) {
                const unsigned short* e0 = (const unsigned short*)&ah4[0];
                const unsigned short* e1 = (const unsigned short*)&ah4[1];
                const unsigned short* e2 = (const unsigned short*)&ah4[2];
                const unsigned short* e3 = (const unsigned short*)&ah4[3];
                uint2 wh, wl;
                wh.x = (unsigned)e0[j] | ((unsigned)e1[j] << 16);
                wh.y = (unsigned)e2[j] | ((unsigned)e3[j] << 16);
                const unsigned short* f0 = (const unsigned short*)&al4[0];
                const unsigned short* f1 = (const unsigned short*)&al4[1];
                const unsigned short* f2 = (const unsigned short*)&al4[2];
                const unsigned short* f3 = (const unsigned short*)&al4[3];
                wl.x = (unsigned)f0[j] | ((unsigned)f1[j] << 16);
                wl.y = (unsigned)f2[j] | ((unsigned)f3[j] << 16);
                *(uint2*)&Vth[vd0 + j][vk0] = wh;
                *(uint2*)&Vtl[vd0 + j][vk0] = wl;
            }
        }
        __syncthreads();

        // --- S = (Q/8) K^T : 4 key-tiles x 2 k-chunks x 3 split terms
        f32x4 s[4];
#pragma unroll
        for (int t = 0; t < 4; ++t) s[t] = fzero;
#pragma unroll
        for (int t = 0; t < 4; ++t)
#pragma unroll
            for (int c = 0; c < 2; ++c) {
                short8 kh = *(const short8*)&Ksh[t*16 + lrow][c*32 + lgrp*8];
                short8 kl = *(const short8*)&Ksl[t*16 + lrow][c*32 + lgrp*8];
                s[t] = __builtin_amdgcn_mfma_f32_16x16x32_bf16(qh[c], kh, s[t], 0, 0, 0);
                s[t] = __builtin_amdgcn_mfma_f32_16x16x32_bf16(ql[c], kh, s[t], 0, 0, 0);
                s[t] = __builtin_amdgcn_mfma_f32_16x16x32_bf16(qh[c], kl, s[t], 0, 0, 0);
            }

        if (kt == rt) {                  // causal mask on the diagonal tile
            const int qloc = wid * 16 + lgrp * 4;
#pragma unroll
            for (int t = 0; t < 4; ++t)
#pragma unroll
                for (int r = 0; r < 4; ++r)
                    if (t*16 + lrow > qloc + r) s[t][r] = -1e30f;
        }

        // --- online softmax (rows = lgrp*4+r; keys spread over lrow & tiles)
        float pm[4];
#pragma unroll
        for (int r = 0; r < 4; ++r)
            pm[r] = fmaxf(fmaxf(s[0][r], s[1][r]), fmaxf(s[2][r], s[3][r]));
#pragma unroll
        for (int off = 8; off >= 1; off >>= 1)
#pragma unroll
            for (int r = 0; r < 4; ++r)
                pm[r] = fmaxf(pm[r], __shfl_xor(pm[r], off));

        float rs[4], rowsum[4];
#pragma unroll
        for (int r = 0; r < 4; ++r) {
            float mn = fmaxf(m[r], pm[r]);
            rs[r] = __expf(m[r] - mn);
            m[r] = mn;
            rowsum[r] = 0.f;
        }
#pragma unroll
        for (int t = 0; t < 4; ++t)
#pragma unroll
            for (int r = 0; r < 4; ++r) {
                float p = __expf(s[t][r] - m[r]);
                s[t][r] = p;
                rowsum[r] += p;
            }
#pragma unroll
        for (int off = 8; off >= 1; off >>= 1)
#pragma unroll
            for (int r = 0; r < 4; ++r)
                rowsum[r] += __shfl_xor(rowsum[r], off);
#pragma unroll
        for (int r = 0; r < 4; ++r) l[r] = l[r] * rs[r] + rowsum[r];
#pragma unroll
        for (int dt = 0; dt < 4; ++dt)
#pragma unroll
            for (int r = 0; r < 4; ++r) o[dt][r] *= rs[r];

        // --- publish P as bf16 (wave-private)
#pragma unroll
        for (int t = 0; t < 4; ++t)
#pragma unroll
            for (int r = 0; r < 4; ++r)
                Ps[wid][lgrp*4 + r][t*16 + lrow] = bf_rnd(s[t][r]);

        // --- O += P V (V 2-term split)
#pragma unroll
        for (int kc = 0; kc < 2; ++kc) {
            short8 pa = *(const short8*)&Ps[wid][lrow][kc*32 + lgrp*8];
#pragma unroll
            for (int dt = 0; dt < 4; ++dt) {
                short8 vh = *(const short8*)&Vth[dt*16 + lrow][kc*32 + lgrp*8];
                short8 vl = *(const short8*)&Vtl[dt*16 + lrow][kc*32 + lgrp*8];
                o[dt] = __builtin_amdgcn_mfma_f32_16x16x32_bf16(pa, vh, o[dt], 0, 0, 0);
                o[dt] = __builtin_amdgcn_mfma_f32_16x16x32_bf16(pa, vl, o[dt], 0, 0, 0);
            }
        }
        __syncthreads();
    }

    // --- epilogue: normalize, split, store both planes
#pragma unroll
    for (int r = 0; r < 4; ++r) {
        float inv = 1.f / l[r];
#pragma unroll
        for (int dt = 0; dt < 4; ++dt) {
            const size_t idx = base + (size_t)(row0 + wid*16 + lgrp*4 + r) * DM + dt*16 + lrow;
            float v = o[dt][r] * inv;
            unsigned short hh = bf_hi(v);
            Oh_g[idx] = hh;
            Ol_g[idx] = bf_hi(v - bf_f(hh));
        }
    }
}

// ---------------------------------------------------------------------------
extern "C" void kernel_launch(void* const* d_in, const int* in_sizes, int n_in,
                              void* d_out, int out_size, void* d_ws, size_t ws_size,
                              hipStream_t stream)
{
    const float* q   = (const float*)d_in[0];
    // d_in[1] = causal mask (static) -> ignored
    const float* w_q = (const float*)d_in[2];
    const float* w_k = (const float*)d_in[3];
    const float* w_v = (const float*)d_in[4];
    const float* w_o = (const float*)d_in[5];
    float* out = (float*)d_out;

    const size_t HN = (size_t)BATCH * S_LEN * DM;   // 8388608 elems, 16 MB/plane
    unsigned short* Qh = (unsigned short*)d_ws;
    unsigned short* Ql = Qh + HN;
    unsigned short* Kh = Ql + HN;
    unsigned short* Kl = Kh + HN;
    unsigned short* Vh = Kl + HN;
    unsigned short* Vl = Vh + HN;                   // total 96 MB
    // Attention output aliases Q planes (block-exclusive rows, read-before-write)
    unsigned short* Oh = Qh;
    unsigned short* Ol = Ql;

    const int M = BATCH * S_LEN;            // 8192
    dim3 blk(256);
    dim3 ggrid(DM / 128, M / 128);          // (8, 64)
    gemm_k<false, true><<<ggrid, blk, 0, stream>>>(q, nullptr, nullptr, w_q,
                                                   nullptr, Qh, Ql, 0.125f, M, DM, DM);
    gemm_k<false, true><<<ggrid, blk, 0, stream>>>(q, nullptr, nullptr, w_k,
                                                   nullptr, Kh, Kl, 1.0f, M, DM, DM);
    gemm_k<false, true><<<ggrid, blk, 0, stream>>>(q, nullptr, nullptr, w_v,
                                                   nullptr, Vh, Vl, 1.0f, M, DM, DM);

    dim3 agrid(S_LEN / 64, BATCH * NH);     // (32, 64)
    attn_mfma<<<agrid, blk, 0, stream>>>(Qh, Ql, Kh, Kl, Vh, Vl, Oh, Ol);

    gemm_k<true, false><<<ggrid, blk, 0, stream>>>(nullptr, Oh, Ol, w_o,
                                                   out, nullptr, nullptr, 1.0f, M, DM, DM);
}